// Round 7
// baseline (662.028 us; speedup 1.0000x reference)
//
#include <hip/hip_runtime.h>
#include <hip/hip_bf16.h>
#include <math.h>

// Problem constants
#define MTOK 16384   // B*N tokens
#define DDIM 1024
#define EEXP 8
#define FDIM 512
#define EFK  4096    // E*F flattened K for second GEMM

typedef __attribute__((ext_vector_type(8))) short short8;   // 8 bf16 = 4 VGPRs (MFMA A/B frag)
typedef __attribute__((ext_vector_type(4))) float floatx4;  // MFMA C/D frag

__device__ __forceinline__ void gld_lds16(const void* g, void* l) {
  // async global->LDS, 16B per lane, dest = wave-uniform base + lane*16
  __builtin_amdgcn_global_load_lds((const __attribute__((address_space(1))) void*)g,
                                   (__attribute__((address_space(3))) void*)l, 16, 0, 0);
}

// Fast exact-GELU via Abramowitz-Stegun 7.1.26 erf approx (|eps| <= 1.5e-7).
__device__ __forceinline__ float gelu_fast(float v) {
  const float z  = v * 0.70710678118654752f;
  const float az = fabsf(z);
  const float t  = __builtin_amdgcn_rcpf(1.f + 0.3275911f * az);
  const float poly = t * (0.254829592f +
                     t * (-0.284496736f +
                     t * (1.421413741f +
                     t * (-1.453152027f +
                     t * 1.061405429f))));
  const float ex = __expf(-az * az);
  float erfv = 1.f - poly * ex;
  erfv = copysignf(erfv, z);
  return 0.5f * v * (1.f + erfv);
}

// ---------------- transpose + fp32->bf16 cast: in [R,C] f32 -> out [C,R] bf16, batched in z
__global__ __launch_bounds__(256) void transpose_cast_kernel(
    const float* __restrict__ in, __hip_bfloat16* __restrict__ out, int R, int C) {
  __shared__ float tile[32][33];
  const float* inb = in + (size_t)blockIdx.z * R * C;
  __hip_bfloat16* outb = out + (size_t)blockIdx.z * R * C;
  const int c0 = blockIdx.x * 32, r0 = blockIdx.y * 32;
  const int tx = threadIdx.x & 31, ty = threadIdx.x >> 5;  // 32 x 8
#pragma unroll
  for (int i = 0; i < 4; ++i)
    tile[ty + i * 8][tx] = inb[(size_t)(r0 + ty + i * 8) * C + (c0 + tx)];
  __syncthreads();
#pragma unroll
  for (int i = 0; i < 4; ++i)
    outb[(size_t)(c0 + ty + i * 8) * R + (r0 + tx)] = __float2bfloat16(tile[tx][ty + i * 8]);
}

// ---------------- Wr [D][E] -> WrT [E][D] (32 KB, trivial)
__global__ __launch_bounds__(256) void wrt_kernel(
    const float* __restrict__ Wr, float* __restrict__ WrT) {
  const int i = blockIdx.x * 256 + threadIdx.x;   // 8192
  const int d = i >> 3, e = i & 7;
  WrT[(size_t)e * DDIM + d] = Wr[(size_t)d * EEXP + e];
}

// ---------------- router softmax + x->bf16 cast, issue-lean version.
// One wave handles 8 tokens: lane = (token-group tg = lane>>3, expert e = lane&7).
// Dot via float4: x4 broadcast across the 8 lanes of a token (L1), WrT[e] rows
// broadcast across the 8 token groups (L1). Softmax = 3x shfl_xor within the
// aligned 8-lane group. Old version read Wr per-lane-per-d = 537 MB of L2
// traffic (the ~90 us aux hog); this one reads WrT once per wave.
__global__ __launch_bounds__(256) void router_cast_kernel(
    const float* __restrict__ x, const float* __restrict__ WrT,
    const float* __restrict__ br, __hip_bfloat16* __restrict__ xbf,
    float* __restrict__ r) {
  const int wid = threadIdx.x >> 6, lane = threadIdx.x & 63;
  const int tok0 = blockIdx.x * 32 + wid * 8;    // wave's 8 tokens
  const int tg = lane >> 3, e = lane & 7;

  // pass 1: coalesced bf16 cast of the wave's 8 token rows (16 KB)
  const float* xw = x + (size_t)tok0 * DDIM;
  __hip_bfloat16* xo = xbf + (size_t)tok0 * DDIM;
#pragma unroll 4
  for (int it = 0; it < 32; ++it) {
    const int o = it * 256 + lane * 4;
    const float4 v = *(const float4*)(xw + o);
    union { ushort4 u; __hip_bfloat16 h[4]; } pk;
    pk.h[0] = __float2bfloat16(v.x); pk.h[1] = __float2bfloat16(v.y);
    pk.h[2] = __float2bfloat16(v.z); pk.h[3] = __float2bfloat16(v.w);
    *(ushort4*)(xo + o) = pk.u;
  }

  // pass 2: per-lane full dot (token tg, expert e); x rows L1-hot from pass 1
  const float* xt = x + (size_t)(tok0 + tg) * DDIM;
  const float* we = WrT + (size_t)e * DDIM;
  float acc = 0.f;
#pragma unroll 4
  for (int d = 0; d < DDIM; d += 4) {
    const float4 xv = *(const float4*)(xt + d);
    const float4 wv = *(const float4*)(we + d);
    acc += xv.x * wv.x + xv.y * wv.y + xv.z * wv.z + xv.w * wv.w;
  }
  const float logit = acc + br[e];
  float mx = logit;
#pragma unroll
  for (int m = 1; m < 8; m <<= 1) mx = fmaxf(mx, __shfl_xor(mx, m));
  const float ex = __expf(logit - mx);
  float s = ex;
#pragma unroll
  for (int m = 1; m < 8; m <<= 1) s += __shfl_xor(s, m);
  r[(size_t)(tok0 + tg) * EEXP + e] = ex / s;
}

// ============================================================================
// R7 GEMM core: m97-PURE. 128x128 tile, BK=32, 256 threads (4 waves, 2Mx2N,
// per-wave 64x64 = 16 acc frags), dbuf 2x16 KiB = 32 KiB LDS -> 3 blocks/CU.
// K-step: { __syncthreads(); stage(t+1) via gld_lds; 8 ds_read_b128; 16 MFMA }
// with ZERO inline asm / sched_barriers — R1-R6 post-mortem: every pinned
// schedule (memory-clobbered waits + sched_barrier(0)) sat at 27-32% MfmaUtil,
// the m141 "order-pinning defeats compiler scheduling" regression class
// (510/874 TF). m97's fully compiler-scheduled version of THIS structure is
// HW-verified at 874-912 TF (m97/m103), and 128^2 beats 256^2 at this
// structure (912 vs 792, m103/m112). Kept verified wins: BK=32 XOR swizzle
// (R4: PMC conflicts = 0), XCD strip-grouping (R1: FETCH 454->115 MB).
//
// LDS layout per buffer (A 8K @0, B 8K @8192): rows are 64 B at BK=32, packed
// 2 rows per 128-B line; 16B slot c of line r' holds (row = 2r' + (u>>2),
// kchunk = u&3) where u = c ^ (r'&7) — XOR involution applied inversely on the
// per-lane GLOBAL source (rule 21: gld_lds dest stays linear). Frag reads:
// 16 lanes spread 2-way per bank group = free (m136; R4-verified).
// ============================================================================
#define STAGE_PTR(gbase, LD, posv)                                              \
  ((gbase) + (size_t)(2 * ((posv) >> 3) + ((((posv) & 7) ^ (((posv) >> 3) & 7)) >> 2)) * (LD) \
           + ((((posv) & 7) ^ (((posv) >> 3) & 7)) & 3) * 8)

#define STAGE4(O, K0)                                                           \
  do {                                                                          \
    gld_lds16(pA0 + (K0), ldsb + (O) + (tid << 4));                             \
    gld_lds16(pA1 + (K0), ldsb + (O) + 4096 + (tid << 4));                      \
    gld_lds16(pB0 + (K0), ldsb + (O) + 8192 + (tid << 4));                      \
    gld_lds16(pB1 + (K0), ldsb + (O) + 12288 + (tid << 4));                     \
  } while (0)

#define GEMM_CORE(NT)                                                           \
  STAGE4(0, 0);                                                                 \
  for (int kt = 0; kt < (NT); ++kt) {                                           \
    __syncthreads();                                                            \
    const int bo = (kt & 1) << 14;                                              \
    if (kt + 1 < (NT)) STAGE4(bo ^ 16384, (kt + 1) * 32);                       \
    _Pragma("unroll") for (int i_ = 0; i_ < 4; ++i_)                            \
      af[i_] = *(const short8*)(ldsb + bo + laneA + i_ * 1024);                 \
    _Pragma("unroll") for (int j_ = 0; j_ < 4; ++j_)                            \
      bf[j_] = *(const short8*)(ldsb + bo + laneB + j_ * 1024);                 \
    _Pragma("unroll") for (int i_ = 0; i_ < 4; ++i_)                            \
      _Pragma("unroll") for (int j_ = 0; j_ < 4; ++j_)                          \
        acc[i_][j_] = __builtin_amdgcn_mfma_f32_16x16x32_bf16(                  \
            af[i_], bf[j_], acc[i_][j_], 0, 0, 0);                              \
  }

// ---------------- GEMM 1: Hs[tok][e*F+f] = bf16( gelu(x @ W1[e] + b1[e]) * r[tok,e] )
// Grid 4096 = strip(128) x e(8) x fb(4); decode keeps all 32 weight-blocks of a
// token strip on ONE XCD (bid%8 == strip%8) -> x strip L2-shared; W1t L3.
__global__ __launch_bounds__(256, 3) void gemm_h_kernel(
    const __hip_bfloat16* __restrict__ A, const __hip_bfloat16* __restrict__ W1t,
    const float* __restrict__ b1, const float* __restrict__ r,
    __hip_bfloat16* __restrict__ Hs) {
  const int bid = blockIdx.x;
  const int strip = (bid >> 8) * 8 + (bid & 7);   // 0..127
  const int wsl = (bid >> 3) & 31;
  const int e = wsl >> 2, fb = wsl & 3;
  const int T0 = strip * 128, F0 = fb * 128;

  __shared__ char ldsb[2 * 16384];   // 32 KiB -> 3 blocks/CU

  const int tid = threadIdx.x, lane = tid & 63, wid = tid >> 6;
  const int wr = wid >> 1, wc = wid & 1;          // 2 x 2 wave grid
  const int lanem = lane & 15, laneq = lane >> 4;
  const int cswz = (((lanem & 1) << 2) | laneq) ^ (lanem >> 1);
  const int laneA = (lanem >> 1) * 128 + cswz * 16 + wr * 4096;
  const int laneB = 8192 + (lanem >> 1) * 128 + cswz * 16 + wc * 4096;

  const __hip_bfloat16* gA = W1t + (size_t)e * FDIM * DDIM + (size_t)F0 * DDIM;
  const __hip_bfloat16* gB = A + (size_t)T0 * DDIM;
  const __hip_bfloat16* pA0 = STAGE_PTR(gA, DDIM, tid);
  const __hip_bfloat16* pA1 = STAGE_PTR(gA, DDIM, tid + 256);
  const __hip_bfloat16* pB0 = STAGE_PTR(gB, DDIM, tid);
  const __hip_bfloat16* pB1 = STAGE_PTR(gB, DDIM, tid + 256);

  floatx4 acc[4][4];
#pragma unroll
  for (int i = 0; i < 4; ++i)
#pragma unroll
    for (int j = 0; j < 4; ++j) acc[i][j] = (floatx4){0.f, 0.f, 0.f, 0.f};
  short8 af[4], bf[4];

  GEMM_CORE(DDIM / 32);

  // epilogue: bias -> fast exact-gelu -> router scale -> packed bf16x4 store
#pragma unroll
  for (int nj = 0; nj < 4; ++nj) {
    const int tok = T0 + wc * 64 + nj * 16 + lanem;
    const float rv = r[(size_t)tok * EEXP + e];
#pragma unroll
    for (int mi = 0; mi < 4; ++mi) {
      const int f = F0 + wr * 64 + mi * 16 + laneq * 4;    // 4 consecutive f
      const float4 b4 = *(const float4*)(b1 + e * FDIM + f);
      union { ushort4 u; __hip_bfloat16 h[4]; } pk;
      pk.h[0] = __float2bfloat16(gelu_fast(acc[mi][nj][0] + b4.x) * rv);
      pk.h[1] = __float2bfloat16(gelu_fast(acc[mi][nj][1] + b4.y) * rv);
      pk.h[2] = __float2bfloat16(gelu_fast(acc[mi][nj][2] + b4.z) * rv);
      pk.h[3] = __float2bfloat16(gelu_fast(acc[mi][nj][3] + b4.w) * rv);
      *(ushort4*)(Hs + (size_t)tok * EFK + e * FDIM + f) = pk.u;
    }
  }
}

// ---------------- GEMM 2: out[tok][d] = Hs[tok,:] @ W2flat[:,d] + sum_e r[tok,e]*b2[e,d]
// Grid 1024 = strip(128) x db(8); the 8 d-blocks of a strip share an XCD
// (bid%8 == strip%8) -> strip's Hs rows (1 MB) L2-shared 8x; W2t (8 MB) L3.
__global__ __launch_bounds__(256, 3) void gemm_out_kernel(
    const __hip_bfloat16* __restrict__ Hs, const __hip_bfloat16* __restrict__ W2t,
    const float* __restrict__ b2, const float* __restrict__ r,
    float* __restrict__ out) {
  const int bid = blockIdx.x;
  const int strip = (bid >> 6) * 8 + (bid & 7);   // 0..127
  const int db = (bid >> 3) & 7;                  // d block
  const int T0 = strip * 128, D0 = db * 128;

  __shared__ char ldsb[2 * 16384];   // 32 KiB -> 3 blocks/CU

  const int tid = threadIdx.x, lane = tid & 63, wid = tid >> 6;
  const int wr = wid >> 1, wc = wid & 1;
  const int lanem = lane & 15, laneq = lane >> 4;
  const int cswz = (((lanem & 1) << 2) | laneq) ^ (lanem >> 1);
  const int laneA = (lanem >> 1) * 128 + cswz * 16 + wr * 4096;
  const int laneB = 8192 + (lanem >> 1) * 128 + cswz * 16 + wc * 4096;

  const __hip_bfloat16* gA = W2t + (size_t)D0 * EFK;
  const __hip_bfloat16* gB = Hs + (size_t)T0 * EFK;
  const __hip_bfloat16* pA0 = STAGE_PTR(gA, EFK, tid);
  const __hip_bfloat16* pA1 = STAGE_PTR(gA, EFK, tid + 256);
  const __hip_bfloat16* pB0 = STAGE_PTR(gB, EFK, tid);
  const __hip_bfloat16* pB1 = STAGE_PTR(gB, EFK, tid + 256);

  floatx4 acc[4][4];
#pragma unroll
  for (int i = 0; i < 4; ++i)
#pragma unroll
    for (int j = 0; j < 4; ++j) acc[i][j] = (floatx4){0.f, 0.f, 0.f, 0.f};
  short8 af[4], bf[4];

  GEMM_CORE(EFK / 32);

  // epilogue: combined bias sum_e r[tok,e]*b2[e,d], float4 store
#pragma unroll
  for (int mi = 0; mi < 4; ++mi) {
    const int d0 = D0 + wr * 64 + mi * 16 + laneq * 4;     // 4 consecutive d
    float4 b2v[EEXP];
#pragma unroll
    for (int e = 0; e < EEXP; ++e) b2v[e] = *(const float4*)(b2 + e * DDIM + d0);
#pragma unroll
    for (int nj = 0; nj < 4; ++nj) {
      const int tok = T0 + wc * 64 + nj * 16 + lanem;
      const float4* r4 = (const float4*)(r + (size_t)tok * EEXP);
      const float4 r0 = r4[0], r1 = r4[1];
      const float rv[EEXP] = {r0.x, r0.y, r0.z, r0.w, r1.x, r1.y, r1.z, r1.w};
      float bx = 0.f, by = 0.f, bz = 0.f, bw = 0.f;
#pragma unroll
      for (int e = 0; e < EEXP; ++e) {
        bx += rv[e] * b2v[e].x; by += rv[e] * b2v[e].y;
        bz += rv[e] * b2v[e].z; bw += rv[e] * b2v[e].w;
      }
      float4 o;
      o.x = acc[mi][nj][0] + bx; o.y = acc[mi][nj][1] + by;
      o.z = acc[mi][nj][2] + bz; o.w = acc[mi][nj][3] + bw;
      *(float4*)(out + (size_t)tok * DDIM + d0) = o;
    }
  }
}

extern "C" void kernel_launch(void* const* d_in, const int* in_sizes, int n_in,
                              void* d_out, int out_size, void* d_ws, size_t ws_size,
                              hipStream_t stream) {
  const float* x  = (const float*)d_in[0];
  const float* W1 = (const float*)d_in[1];
  const float* b1 = (const float*)d_in[2];
  const float* W2 = (const float*)d_in[3];
  const float* b2 = (const float*)d_in[4];
  const float* Wr = (const float*)d_in[5];
  const float* br = (const float*)d_in[6];
  float* out = (float*)d_out;

  char* ws = (char*)d_ws;
  __hip_bfloat16* xbf = (__hip_bfloat16*)(ws);                            // 32 MB
  __hip_bfloat16* W1t = (__hip_bfloat16*)(ws + (32u << 20));              // 8 MB  [E][F][D]
  __hip_bfloat16* W2t = (__hip_bfloat16*)(ws + (40u << 20));              // 8 MB  [D][E*F]
  float*          r   = (float*)(ws + (48u << 20));                       // 0.5 MB [MTOK][E]
  __hip_bfloat16* Hs  = (__hip_bfloat16*)(ws + (48u << 20) + (1u << 19)); // 128 MB [MTOK][E*F]
  float*          WrT = (float*)(ws + (176u << 20) + (1u << 19));         // 32 KB [E][D]

  // Wr [D][E] -> WrT [E][D]
  wrt_kernel<<<32, 256, 0, stream>>>(Wr, WrT);
  // W1 [E][D][F] -> W1t [E][F][D]
  transpose_cast_kernel<<<dim3(FDIM / 32, DDIM / 32, EEXP), 256, 0, stream>>>(W1, W1t, DDIM, FDIM);
  // W2 [E*F][D] -> W2t [D][E*F]
  transpose_cast_kernel<<<dim3(DDIM / 32, EFK / 32, 1), 256, 0, stream>>>(W2, W2t, EFK, DDIM);
  // router softmax + x cast (wave = 8 tokens, lane = (token, expert))
  router_cast_kernel<<<MTOK / 32, 256, 0, stream>>>(x, WrT, br, xbf, r);
  // stage 1 grouped GEMM (+gelu, +router scale): 128-f x 128-tok tiles
  gemm_h_kernel<<<dim3((MTOK / 128) * (FDIM / 128) * EEXP), 256, 0, stream>>>(xbf, W1t, b1, r, Hs);
  // stage 2 GEMM (+combined bias): 128-d x 128-tok tiles, XCD-grouped strips
  gemm_out_kernel<<<dim3((MTOK / 128) * (DDIM / 128)), 256, 0, stream>>>(Hs, W2t, b2, r, out);
}

// Round 8
// 537.436 us; speedup vs baseline: 1.2318x; 1.2318x over previous
//
#include <hip/hip_runtime.h>
#include <hip/hip_bf16.h>
#include <math.h>

// Problem constants
#define MTOK 16384   // B*N tokens
#define DDIM 1024
#define EEXP 8
#define FDIM 512
#define EFK  4096    // E*F flattened K for second GEMM

typedef __attribute__((ext_vector_type(8))) short short8;   // 8 bf16 = 4 VGPRs (MFMA A/B frag)
typedef __attribute__((ext_vector_type(4))) float floatx4;  // MFMA C/D frag

__device__ __forceinline__ void gld_lds16(const void* g, void* l) {
  // async global->LDS, 16B per lane, dest = wave-uniform base + lane*16
  __builtin_amdgcn_global_load_lds((const __attribute__((address_space(1))) void*)g,
                                   (__attribute__((address_space(3))) void*)l, 16, 0, 0);
}

// Fast exact-GELU via Abramowitz-Stegun 7.1.26 erf approx (|eps| <= 1.5e-7).
__device__ __forceinline__ float gelu_fast(float v) {
  const float z  = v * 0.70710678118654752f;
  const float az = fabsf(z);
  const float t  = __builtin_amdgcn_rcpf(1.f + 0.3275911f * az);
  const float poly = t * (0.254829592f +
                     t * (-0.284496736f +
                     t * (1.421413741f +
                     t * (-1.453152027f +
                     t * 1.061405429f))));
  const float ex = __expf(-az * az);
  float erfv = 1.f - poly * ex;
  erfv = copysignf(erfv, z);
  return 0.5f * v * (1.f + erfv);
}

// ---------------- transpose + fp32->bf16 cast: in [R,C] f32 -> out [C,R] bf16, batched in z
__global__ __launch_bounds__(256) void transpose_cast_kernel(
    const float* __restrict__ in, __hip_bfloat16* __restrict__ out, int R, int C) {
  __shared__ float tile[32][33];
  const float* inb = in + (size_t)blockIdx.z * R * C;
  __hip_bfloat16* outb = out + (size_t)blockIdx.z * R * C;
  const int c0 = blockIdx.x * 32, r0 = blockIdx.y * 32;
  const int tx = threadIdx.x & 31, ty = threadIdx.x >> 5;  // 32 x 8
#pragma unroll
  for (int i = 0; i < 4; ++i)
    tile[ty + i * 8][tx] = inb[(size_t)(r0 + ty + i * 8) * C + (c0 + tx)];
  __syncthreads();
#pragma unroll
  for (int i = 0; i < 4; ++i)
    outb[(size_t)(c0 + ty + i * 8) * R + (r0 + tx)] = __float2bfloat16(tile[tx][ty + i * 8]);
}

// ---------------- Wr [D][E] -> WrT [E][D] (32 KB, trivial)
__global__ __launch_bounds__(256) void wrt_kernel(
    const float* __restrict__ Wr, float* __restrict__ WrT) {
  const int i = blockIdx.x * 256 + threadIdx.x;   // 8192
  const int d = i >> 3, e = i & 7;
  WrT[(size_t)e * DDIM + d] = Wr[(size_t)d * EEXP + e];
}

// ---------------- router softmax + x->bf16 cast, issue-lean version (R7-validated).
// One wave handles 8 tokens: lane = (token-group tg = lane>>3, expert e = lane&7).
// Dot via float4: x rows L1-hot from pass 1, WrT[e] rows L1-broadcast across the
// 8 token groups. Softmax = 3x shfl_xor within the aligned 8-lane group. The old
// one-wave-per-token router (scalar x loads + 32 B/lane of Wr per d) was the
// ~60-80 us aux hog; this one is ~3x leaner on issue and memory.
__global__ __launch_bounds__(256) void router_cast_kernel(
    const float* __restrict__ x, const float* __restrict__ WrT,
    const float* __restrict__ br, __hip_bfloat16* __restrict__ xbf,
    float* __restrict__ r) {
  const int wid = threadIdx.x >> 6, lane = threadIdx.x & 63;
  const int tok0 = blockIdx.x * 32 + wid * 8;    // wave's 8 tokens
  const int tg = lane >> 3, e = lane & 7;

  // pass 1: coalesced bf16 cast of the wave's 8 token rows (16 KB)
  const float* xw = x + (size_t)tok0 * DDIM;
  __hip_bfloat16* xo = xbf + (size_t)tok0 * DDIM;
#pragma unroll 4
  for (int it = 0; it < 32; ++it) {
    const int o = it * 256 + lane * 4;
    const float4 v = *(const float4*)(xw + o);
    union { ushort4 u; __hip_bfloat16 h[4]; } pk;
    pk.h[0] = __float2bfloat16(v.x); pk.h[1] = __float2bfloat16(v.y);
    pk.h[2] = __float2bfloat16(v.z); pk.h[3] = __float2bfloat16(v.w);
    *(ushort4*)(xo + o) = pk.u;
  }

  // pass 2: per-lane full dot (token tg, expert e); x rows L1-hot from pass 1
  const float* xt = x + (size_t)(tok0 + tg) * DDIM;
  const float* we = WrT + (size_t)e * DDIM;
  float acc = 0.f;
#pragma unroll 4
  for (int d = 0; d < DDIM; d += 4) {
    const float4 xv = *(const float4*)(xt + d);
    const float4 wv = *(const float4*)(we + d);
    acc += xv.x * wv.x + xv.y * wv.y + xv.z * wv.z + xv.w * wv.w;
  }
  const float logit = acc + br[e];
  float mx = logit;
#pragma unroll
  for (int m = 1; m < 8; m <<= 1) mx = fmaxf(mx, __shfl_xor(mx, m));
  const float ex = __expf(logit - mx);
  float s = ex;
#pragma unroll
  for (int m = 1; m < 8; m <<= 1) s += __shfl_xor(s, m);
  r[(size_t)(tok0 + tg) * EEXP + e] = ex / s;
}

// ============================================================================
// R8 GEMM core = R3-EXACT (measured best of 7 structural variants: gemm_out
// 181.6 us, 32% MfmaUtil, 759 TF — in the plain-HIP grouped-GEMM band
// m248: 655-848 TF). 256x256 tile, BK=64, 8 waves (2Mx4N), ONE barrier per
// K-tile, counted lgkm gates, XOR swizzle (PMC conflicts = 0), XCD grouping
// (FETCH 115 MB). GEMMs are the CONTROL this round; only aux changed.
// ============================================================================
#define BUFSZ 65536
#define AOFF  0
#define BOFF  32768

#define STAGE_A(Q1, QM, K0)                                                        \
  do {                                                                             \
    _Pragma("unroll") for (int r_ = 0; r_ < 2; ++r_) {                             \
      gld_lds16(gA + (size_t)(r_ * 128 + (QM) * 64 + wid * 8 + l3) * LDA_ +        \
                    (K0) + ((l7 ^ l3) * 8),                                        \
                ldsb + (Q1) * BUFSZ + AOFF + (QM) * 16384 +                        \
                    (r_ * 64 + wid * 8) * 128);                                    \
    }                                                                              \
  } while (0)

#define STAGE_B(Q1, QN, K0)                                                        \
  do {                                                                             \
    _Pragma("unroll") for (int r_ = 0; r_ < 2; ++r_) {                             \
      const int lin_ = r_ * 64 + wid * 8 + l3;                                     \
      gld_lds16(gB + (size_t)((lin_ >> 5) * 64 + (QN) * 32 + (lin_ & 31)) * LDB_ + \
                    (K0) + ((l7 ^ l3) * 8),                                        \
                ldsb + (Q1) * BUFSZ + BOFF + (QN) * 16384 +                        \
                    (r_ * 64 + wid * 8) * 128);                                    \
    }                                                                              \
  } while (0)

#define STAGE_ALL(Q1, K0)                                                          \
  do { STAGE_A(Q1, 0, K0); STAGE_B(Q1, 0, K0); STAGE_B(Q1, 1, K0);                 \
       STAGE_A(Q1, 1, K0); } while (0)

#define READS_A(P, QM)                                                             \
  _Pragma("unroll") for (int i_ = 0; i_ < 4; ++i_)                                 \
    _Pragma("unroll") for (int k_ = 0; k_ < 2; ++k_)                               \
      af[QM][i_][k_] = *(const short8*)(ldsb + (P) * BUFSZ + AOFF +                \
          (QM) * 16384 + (wr * 64 + i_ * 16 + lanem) * 128 +                       \
          (((k_ * 4 + laneq) ^ swz) * 16));

#define READS_B(P)                                                                 \
  _Pragma("unroll") for (int n_ = 0; n_ < 4; ++n_)                                 \
    _Pragma("unroll") for (int k_ = 0; k_ < 2; ++k_)                               \
      bf[n_][k_] = *(const short8*)(ldsb + (P) * BUFSZ + BOFF +                    \
          (n_ >> 1) * 16384 + (wc * 32 + (n_ & 1) * 16 + lanem) * 128 +            \
          (((k_ * 4 + laneq) ^ swz) * 16));

#define MFMA_Q(QM, QN)                                                             \
  _Pragma("unroll") for (int k_ = 0; k_ < 2; ++k_)                                 \
    _Pragma("unroll") for (int i_ = 0; i_ < 4; ++i_)                               \
      _Pragma("unroll") for (int j_ = 0; j_ < 2; ++j_)                             \
        acc[(QM) * 4 + i_][(QN) * 2 + j_] =                                        \
            __builtin_amdgcn_mfma_f32_16x16x32_bf16(                               \
                af[QM][i_][k_], bf[(QN) * 2 + j_][k_],                             \
                acc[(QM) * 4 + i_][(QN) * 2 + j_], 0, 0, 0);

#define LGKM(N)                                                                    \
  asm volatile("s_waitcnt lgkmcnt(" #N ")" ::: "memory");                          \
  __builtin_amdgcn_sched_barrier(0)

#define GEMM_CORE(NT)                                                              \
  STAGE_ALL(0, 0);                                                                 \
  asm volatile("s_waitcnt vmcnt(0)\n\ts_barrier" ::: "memory");                    \
  for (int kt = 0; kt < (NT); ++kt) {                                              \
    const int p_ = kt & 1;                                                         \
    if (kt + 1 < (NT)) STAGE_ALL(p_ ^ 1, (kt + 1) * 64);                           \
    READS_A(p_, 0);                                                                \
    READS_B(p_);                                                                   \
    __builtin_amdgcn_sched_barrier(0);                                             \
    READS_A(p_, 1);                                                                \
    __builtin_amdgcn_sched_barrier(0);                                             \
    LGKM(12);                                                                      \
    __builtin_amdgcn_s_setprio(1);                                                 \
    MFMA_Q(0, 0);                                                                  \
    __builtin_amdgcn_s_setprio(0);                                                 \
    LGKM(8);                                                                       \
    __builtin_amdgcn_s_setprio(1);                                                 \
    MFMA_Q(0, 1);                                                                  \
    __builtin_amdgcn_s_setprio(0);                                                 \
    LGKM(0);                                                                       \
    __builtin_amdgcn_s_setprio(1);                                                 \
    MFMA_Q(1, 1);                                                                  \
    MFMA_Q(1, 0);                                                                  \
    __builtin_amdgcn_s_setprio(0);                                                 \
    asm volatile("s_waitcnt vmcnt(0)\n\ts_barrier" ::: "memory");                  \
  }

// ---------------- GEMM 1: Hs[tok][e*F+f] = bf16( gelu(x @ W1[e] + b1[e]) * r[tok,e] )
// Grid: 1024 blocks = e(8) x fb(2) x strip(64); strip fastest so the 16 blocks
// sharing a token strip are 64 apart in bid -> same XCD (64%8==0) -> x strip
// L2-resident; each (e,fb) weight slice dispatch-adjacent.
__global__ __launch_bounds__(512, 2) void gemm_h_kernel(
    const __hip_bfloat16* __restrict__ A, const __hip_bfloat16* __restrict__ W1t,
    const float* __restrict__ b1, const float* __restrict__ r,
    __hip_bfloat16* __restrict__ Hs) {
  const int bid = blockIdx.x;
  const int strip = bid & 63, fb = (bid >> 6) & 1, e = bid >> 7;
  const int T0 = strip * 256, F0 = fb * 256;

  __shared__ char ldsb[2 * BUFSZ];   // 128 KiB

  const int tid = threadIdx.x, lane = tid & 63, wid = tid >> 6;
  const int wr = wid >> 2, wc = wid & 3;       // 2 x 4 wave grid
  const int lanem = lane & 15, laneq = lane >> 4;
  const int l3 = lane >> 3, l7 = lane & 7;     // staging lane decompose
  const int swz = lanem & 7;
  const int LDA_ = DDIM, LDB_ = DDIM;

  const __hip_bfloat16* gA = W1t + (size_t)e * FDIM * DDIM + (size_t)F0 * DDIM;
  const __hip_bfloat16* gB = A + (size_t)T0 * DDIM;

  floatx4 acc[8][4];
#pragma unroll
  for (int i = 0; i < 8; ++i)
#pragma unroll
    for (int j = 0; j < 4; ++j) acc[i][j] = (floatx4){0.f, 0.f, 0.f, 0.f};
  short8 af[2][4][2], bf[4][2];

  GEMM_CORE(DDIM / 64);

  // epilogue: bias -> fast exact-gelu -> router scale -> packed bf16x4 store
#pragma unroll
  for (int nj = 0; nj < 4; ++nj) {
    const int tok = T0 + wc * 64 + nj * 16 + lanem;
    const float rv = r[(size_t)tok * EEXP + e];
#pragma unroll
    for (int mi = 0; mi < 8; ++mi) {
      const int f = F0 + wr * 128 + mi * 16 + laneq * 4;   // 4 consecutive f
      const float4 b4 = *(const float4*)(b1 + e * FDIM + f);
      union { ushort4 u; __hip_bfloat16 h[4]; } pk;
      pk.h[0] = __float2bfloat16(gelu_fast(acc[mi][nj][0] + b4.x) * rv);
      pk.h[1] = __float2bfloat16(gelu_fast(acc[mi][nj][1] + b4.y) * rv);
      pk.h[2] = __float2bfloat16(gelu_fast(acc[mi][nj][2] + b4.z) * rv);
      pk.h[3] = __float2bfloat16(gelu_fast(acc[mi][nj][3] + b4.w) * rv);
      *(ushort4*)(Hs + (size_t)tok * EFK + e * FDIM + f) = pk.u;
    }
  }
}

// ---------------- GEMM 2: out[tok][d] = Hs[tok,:] @ W2flat[:,d] + sum_e r[tok,e]*b2[e,d]
// Grid: 256 blocks; decode puts the 4 d-quarter blocks of one token strip on
// the SAME XCD (bid%8 == strip%8) -> the strip's Hs rows L2-shared 4x.
__global__ __launch_bounds__(512, 2) void gemm_out_kernel(
    const __hip_bfloat16* __restrict__ Hs, const __hip_bfloat16* __restrict__ W2t,
    const float* __restrict__ b2, const float* __restrict__ r,
    float* __restrict__ out) {
  const int bid = blockIdx.x;
  const int strip = (bid >> 5) * 8 + (bid & 7);   // 0..63 token strip
  const int dq = (bid >> 3) & 3;                  // d quarter
  const int T0 = strip * 256, D0 = dq * 256;

  __shared__ char ldsb[2 * BUFSZ];   // 128 KiB

  const int tid = threadIdx.x, lane = tid & 63, wid = tid >> 6;
  const int wr = wid >> 2, wc = wid & 3;
  const int lanem = lane & 15, laneq = lane >> 4;
  const int l3 = lane >> 3, l7 = lane & 7;
  const int swz = lanem & 7;
  const int LDA_ = EFK, LDB_ = EFK;

  const __hip_bfloat16* gA = W2t + (size_t)D0 * EFK;
  const __hip_bfloat16* gB = Hs + (size_t)T0 * EFK;

  floatx4 acc[8][4];
#pragma unroll
  for (int i = 0; i < 8; ++i)
#pragma unroll
    for (int j = 0; j < 4; ++j) acc[i][j] = (floatx4){0.f, 0.f, 0.f, 0.f};
  short8 af[2][4][2], bf[4][2];

  GEMM_CORE(EFK / 64);

  // epilogue: combined bias sum_e r[tok,e]*b2[e,d], float4 store
#pragma unroll
  for (int mi = 0; mi < 8; ++mi) {
    const int d0 = D0 + wr * 128 + mi * 16 + laneq * 4;    // 4 consecutive d
    float4 b2v[EEXP];
#pragma unroll
    for (int e = 0; e < EEXP; ++e) b2v[e] = *(const float4*)(b2 + e * DDIM + d0);
#pragma unroll
    for (int nj = 0; nj < 4; ++nj) {
      const int tok = T0 + wc * 64 + nj * 16 + lanem;
      const float4* r4 = (const float4*)(r + (size_t)tok * EEXP);
      const float4 r0 = r4[0], r1 = r4[1];
      const float rv[EEXP] = {r0.x, r0.y, r0.z, r0.w, r1.x, r1.y, r1.z, r1.w};
      float bx = 0.f, by = 0.f, bz = 0.f, bw = 0.f;
#pragma unroll
      for (int e = 0; e < EEXP; ++e) {
        bx += rv[e] * b2v[e].x; by += rv[e] * b2v[e].y;
        bz += rv[e] * b2v[e].z; bw += rv[e] * b2v[e].w;
      }
      float4 o;
      o.x = acc[mi][nj][0] + bx; o.y = acc[mi][nj][1] + by;
      o.z = acc[mi][nj][2] + bz; o.w = acc[mi][nj][3] + bw;
      *(float4*)(out + (size_t)tok * DDIM + d0) = o;
    }
  }
}

extern "C" void kernel_launch(void* const* d_in, const int* in_sizes, int n_in,
                              void* d_out, int out_size, void* d_ws, size_t ws_size,
                              hipStream_t stream) {
  const float* x  = (const float*)d_in[0];
  const float* W1 = (const float*)d_in[1];
  const float* b1 = (const float*)d_in[2];
  const float* W2 = (const float*)d_in[3];
  const float* b2 = (const float*)d_in[4];
  const float* Wr = (const float*)d_in[5];
  const float* br = (const float*)d_in[6];
  float* out = (float*)d_out;

  char* ws = (char*)d_ws;
  __hip_bfloat16* xbf = (__hip_bfloat16*)(ws);                            // 32 MB
  __hip_bfloat16* W1t = (__hip_bfloat16*)(ws + (32u << 20));              // 8 MB  [E][F][D]
  __hip_bfloat16* W2t = (__hip_bfloat16*)(ws + (40u << 20));              // 8 MB  [D][E*F]
  float*          r   = (float*)(ws + (48u << 20));                       // 0.5 MB [MTOK][E]
  __hip_bfloat16* Hs  = (__hip_bfloat16*)(ws + (48u << 20) + (1u << 19)); // 128 MB [MTOK][E*F]
  float*          WrT = (float*)(ws + (176u << 20) + (1u << 19));         // 32 KB [E][D]

  // Wr [D][E] -> WrT [E][D]
  wrt_kernel<<<32, 256, 0, stream>>>(Wr, WrT);
  // W1 [E][D][F] -> W1t [E][F][D]
  transpose_cast_kernel<<<dim3(FDIM / 32, DDIM / 32, EEXP), 256, 0, stream>>>(W1, W1t, DDIM, FDIM);
  // W2 [E*F][D] -> W2t [D][E*F]
  transpose_cast_kernel<<<dim3(DDIM / 32, EFK / 32, 1), 256, 0, stream>>>(W2, W2t, EFK, DDIM);
  // router softmax + x cast (wave = 8 tokens, lane = (token, expert))
  router_cast_kernel<<<MTOK / 32, 256, 0, stream>>>(x, WrT, br, xbf, r);
  // stage 1 grouped GEMM (+gelu, +router scale): 256-f x 256-tok tiles
  gemm_h_kernel<<<dim3((MTOK / 256) * (FDIM / 256) * EEXP), 512, 0, stream>>>(xbf, W1t, b1, r, Hs);
  // stage 2 GEMM (+combined bias): 256-d x 256-tok tiles, XCD-grouped strips
  gemm_out_kernel<<<dim3((MTOK / 256) * (DDIM / 256)), 512, 0, stream>>>(Hs, W2t, b2, r, out);
}

// Round 9
// 479.621 us; speedup vs baseline: 1.3803x; 1.1205x over previous
//
#include <hip/hip_runtime.h>
#include <hip/hip_bf16.h>
#include <math.h>

// Problem constants
#define MTOK 16384   // B*N tokens
#define DDIM 1024
#define EEXP 8
#define FDIM 512
#define EFK  4096    // E*F flattened K for second GEMM

typedef __attribute__((ext_vector_type(8))) short short8;   // 8 bf16 = 4 VGPRs (MFMA A/B frag)
typedef __attribute__((ext_vector_type(4))) float floatx4;  // MFMA C/D frag

__device__ __forceinline__ void gld_lds16(const void* g, void* l) {
  // async global->LDS, 16B per lane, dest = wave-uniform base + lane*16
  __builtin_amdgcn_global_load_lds((const __attribute__((address_space(1))) void*)g,
                                   (__attribute__((address_space(3))) void*)l, 16, 0, 0);
}

// Fast exact-GELU via Abramowitz-Stegun 7.1.26 erf approx (|eps| <= 1.5e-7).
__device__ __forceinline__ float gelu_fast(float v) {
  const float z  = v * 0.70710678118654752f;
  const float az = fabsf(z);
  const float t  = __builtin_amdgcn_rcpf(1.f + 0.3275911f * az);
  const float poly = t * (0.254829592f +
                     t * (-0.284496736f +
                     t * (1.421413741f +
                     t * (-1.453152027f +
                     t * 1.061405429f))));
  const float ex = __expf(-az * az);
  float erfv = 1.f - poly * ex;
  erfv = copysignf(erfv, z);
  return 0.5f * v * (1.f + erfv);
}

// ---------------- transpose + fp32->bf16 cast: in [R,C] f32 -> out [C,R] bf16, batched in z
__global__ __launch_bounds__(256) void transpose_cast_kernel(
    const float* __restrict__ in, __hip_bfloat16* __restrict__ out, int R, int C) {
  __shared__ float tile[32][33];
  const float* inb = in + (size_t)blockIdx.z * R * C;
  __hip_bfloat16* outb = out + (size_t)blockIdx.z * R * C;
  const int c0 = blockIdx.x * 32, r0 = blockIdx.y * 32;
  const int tx = threadIdx.x & 31, ty = threadIdx.x >> 5;  // 32 x 8
#pragma unroll
  for (int i = 0; i < 4; ++i)
    tile[ty + i * 8][tx] = inb[(size_t)(r0 + ty + i * 8) * C + (c0 + tx)];
  __syncthreads();
#pragma unroll
  for (int i = 0; i < 4; ++i)
    outb[(size_t)(c0 + ty + i * 8) * R + (r0 + tx)] = __float2bfloat16(tile[tx][ty + i * 8]);
}

// ---------------- router softmax (fp32) + x -> bf16 cast. One wave per token
// (R3-proven structure, 4096 blocks). Micro-fix vs R3: each lane handles 2
// consecutive d per iter -> float2 x loads, ushort2 xbf stores (halves the
// cast-path issue count); Wr access stays contiguous 64 B/lane, L1-resident.
__global__ __launch_bounds__(256) void router_cast_kernel(
    const float* __restrict__ x, const float* __restrict__ Wr, const float* __restrict__ br,
    __hip_bfloat16* __restrict__ xbf, float* __restrict__ r) {
  const int wave = (blockIdx.x * 256 + threadIdx.x) >> 6;  // token id
  const int lane = threadIdx.x & 63;
  const float* xr = x + (size_t)wave * DDIM;
  float acc[EEXP];
#pragma unroll
  for (int e = 0; e < EEXP; ++e) acc[e] = 0.f;
#pragma unroll
  for (int i = 0; i < DDIM / 128; ++i) {
    const int d = i * 128 + lane * 2;
    const float2 xv = *(const float2*)(xr + d);
    union { ushort2 u; __hip_bfloat16 h[2]; } pk;
    pk.h[0] = __float2bfloat16(xv.x);
    pk.h[1] = __float2bfloat16(xv.y);
    *(ushort2*)(xbf + (size_t)wave * DDIM + d) = pk.u;
    const float4* w4 = (const float4*)(Wr + (size_t)d * EEXP);
    const float4 w0 = w4[0], w1 = w4[1];   // row d
    const float4 w2 = w4[2], w3 = w4[3];   // row d+1
    acc[0] += xv.x * w0.x + xv.y * w2.x;
    acc[1] += xv.x * w0.y + xv.y * w2.y;
    acc[2] += xv.x * w0.z + xv.y * w2.z;
    acc[3] += xv.x * w0.w + xv.y * w2.w;
    acc[4] += xv.x * w1.x + xv.y * w3.x;
    acc[5] += xv.x * w1.y + xv.y * w3.y;
    acc[6] += xv.x * w1.z + xv.y * w3.z;
    acc[7] += xv.x * w1.w + xv.y * w3.w;
  }
#pragma unroll
  for (int off = 32; off; off >>= 1) {
#pragma unroll
    for (int e = 0; e < EEXP; ++e) acc[e] += __shfl_xor(acc[e], off, 64);
  }
  float mx = -1e30f;
#pragma unroll
  for (int e = 0; e < EEXP; ++e) { acc[e] += br[e]; mx = fmaxf(mx, acc[e]); }
  float s = 0.f;
#pragma unroll
  for (int e = 0; e < EEXP; ++e) { acc[e] = expf(acc[e] - mx); s += acc[e]; }
  const float inv = 1.f / s;
  if (lane < EEXP) r[(size_t)wave * EEXP + lane] = acc[lane] * inv;
}

// ============================================================================
// GEMM core = R3-EXACT (measured best of 7 structural variants: gemm_out
// 181.6 us, 32% MfmaUtil, 759 TF — in the plain-HIP grouped-GEMM band
// m248: 655-848 TF). 256x256 tile, BK=64, 8 waves (2Mx4N), ONE barrier per
// K-tile, counted lgkm gates, XOR swizzle (PMC conflicts = 0), XCD grouping
// (FETCH 115 MB). GEMMs unchanged again this round — controls.
// ============================================================================
#define BUFSZ 65536
#define AOFF  0
#define BOFF  32768

#define STAGE_A(Q1, QM, K0)                                                        \
  do {                                                                             \
    _Pragma("unroll") for (int r_ = 0; r_ < 2; ++r_) {                             \
      gld_lds16(gA + (size_t)(r_ * 128 + (QM) * 64 + wid * 8 + l3) * LDA_ +        \
                    (K0) + ((l7 ^ l3) * 8),                                        \
                ldsb + (Q1) * BUFSZ + AOFF + (QM) * 16384 +                        \
                    (r_ * 64 + wid * 8) * 128);                                    \
    }                                                                              \
  } while (0)

#define STAGE_B(Q1, QN, K0)                                                        \
  do {                                                                             \
    _Pragma("unroll") for (int r_ = 0; r_ < 2; ++r_) {                             \
      const int lin_ = r_ * 64 + wid * 8 + l3;                                     \
      gld_lds16(gB + (size_t)((lin_ >> 5) * 64 + (QN) * 32 + (lin_ & 31)) * LDB_ + \
                    (K0) + ((l7 ^ l3) * 8),                                        \
                ldsb + (Q1) * BUFSZ + BOFF + (QN) * 16384 +                        \
                    (r_ * 64 + wid * 8) * 128);                                    \
    }                                                                              \
  } while (0)

#define STAGE_ALL(Q1, K0)                                                          \
  do { STAGE_A(Q1, 0, K0); STAGE_B(Q1, 0, K0); STAGE_B(Q1, 1, K0);                 \
       STAGE_A(Q1, 1, K0); } while (0)

#define READS_A(P, QM)                                                             \
  _Pragma("unroll") for (int i_ = 0; i_ < 4; ++i_)                                 \
    _Pragma("unroll") for (int k_ = 0; k_ < 2; ++k_)                               \
      af[QM][i_][k_] = *(const short8*)(ldsb + (P) * BUFSZ + AOFF +                \
          (QM) * 16384 + (wr * 64 + i_ * 16 + lanem) * 128 +                       \
          (((k_ * 4 + laneq) ^ swz) * 16));

#define READS_B(P)                                                                 \
  _Pragma("unroll") for (int n_ = 0; n_ < 4; ++n_)                                 \
    _Pragma("unroll") for (int k_ = 0; k_ < 2; ++k_)                               \
      bf[n_][k_] = *(const short8*)(ldsb + (P) * BUFSZ + BOFF +                    \
          (n_ >> 1) * 16384 + (wc * 32 + (n_ & 1) * 16 + lanem) * 128 +            \
          (((k_ * 4 + laneq) ^ swz) * 16));

#define MFMA_Q(QM, QN)                                                             \
  _Pragma("unroll") for (int k_ = 0; k_ < 2; ++k_)                                 \
    _Pragma("unroll") for (int i_ = 0; i_ < 4; ++i_)                               \
      _Pragma("unroll") for (int j_ = 0; j_ < 2; ++j_)                             \
        acc[(QM) * 4 + i_][(QN) * 2 + j_] =                                        \
            __builtin_amdgcn_mfma_f32_16x16x32_bf16(                               \
                af[QM][i_][k_], bf[(QN) * 2 + j_][k_],                             \
                acc[(QM) * 4 + i_][(QN) * 2 + j_], 0, 0, 0);

#define LGKM(N)                                                                    \
  asm volatile("s_waitcnt lgkmcnt(" #N ")" ::: "memory");                          \
  __builtin_amdgcn_sched_barrier(0)

#define GEMM_CORE(NT)                                                              \
  STAGE_ALL(0, 0);                                                                 \
  asm volatile("s_waitcnt vmcnt(0)\n\ts_barrier" ::: "memory");                    \
  for (int kt = 0; kt < (NT); ++kt) {                                              \
    const int p_ = kt & 1;                                                         \
    if (kt + 1 < (NT)) STAGE_ALL(p_ ^ 1, (kt + 1) * 64);                           \
    READS_A(p_, 0);                                                                \
    READS_B(p_);                                                                   \
    __builtin_amdgcn_sched_barrier(0);                                             \
    READS_A(p_, 1);                                                                \
    __builtin_amdgcn_sched_barrier(0);                                             \
    LGKM(12);                                                                      \
    __builtin_amdgcn_s_setprio(1);                                                 \
    MFMA_Q(0, 0);                                                                  \
    __builtin_amdgcn_s_setprio(0);                                                 \
    LGKM(8);                                                                       \
    __builtin_amdgcn_s_setprio(1);                                                 \
    MFMA_Q(0, 1);                                                                  \
    __builtin_amdgcn_s_setprio(0);                                                 \
    LGKM(0);                                                                       \
    __builtin_amdgcn_s_setprio(1);                                                 \
    MFMA_Q(1, 1);                                                                  \
    MFMA_Q(1, 0);                                                                  \
    __builtin_amdgcn_s_setprio(0);                                                 \
    asm volatile("s_waitcnt vmcnt(0)\n\ts_barrier" ::: "memory");                  \
  }

// ---------------- GEMM 1: Hs[tok][e*F+f] = bf16( gelu(x @ W1[e] + b1[e]) * r[tok,e] )
// Grid: 1024 blocks = e(8) x fb(2) x strip(64); strip fastest so the 16 blocks
// sharing a token strip are 64 apart in bid -> same XCD (64%8==0) -> x strip
// L2-resident; each (e,fb) weight slice dispatch-adjacent.
__global__ __launch_bounds__(512, 2) void gemm_h_kernel(
    const __hip_bfloat16* __restrict__ A, const __hip_bfloat16* __restrict__ W1t,
    const float* __restrict__ b1, const float* __restrict__ r,
    __hip_bfloat16* __restrict__ Hs) {
  const int bid = blockIdx.x;
  const int strip = bid & 63, fb = (bid >> 6) & 1, e = bid >> 7;
  const int T0 = strip * 256, F0 = fb * 256;

  __shared__ char ldsb[2 * BUFSZ];   // 128 KiB

  const int tid = threadIdx.x, lane = tid & 63, wid = tid >> 6;
  const int wr = wid >> 2, wc = wid & 3;       // 2 x 4 wave grid
  const int lanem = lane & 15, laneq = lane >> 4;
  const int l3 = lane >> 3, l7 = lane & 7;     // staging lane decompose
  const int swz = lanem & 7;
  const int LDA_ = DDIM, LDB_ = DDIM;

  const __hip_bfloat16* gA = W1t + (size_t)e * FDIM * DDIM + (size_t)F0 * DDIM;
  const __hip_bfloat16* gB = A + (size_t)T0 * DDIM;

  floatx4 acc[8][4];
#pragma unroll
  for (int i = 0; i < 8; ++i)
#pragma unroll
    for (int j = 0; j < 4; ++j) acc[i][j] = (floatx4){0.f, 0.f, 0.f, 0.f};
  short8 af[2][4][2], bf[4][2];

  GEMM_CORE(DDIM / 64);

  // epilogue: bias -> fast exact-gelu -> router scale -> packed bf16x4 store
#pragma unroll
  for (int nj = 0; nj < 4; ++nj) {
    const int tok = T0 + wc * 64 + nj * 16 + lanem;
    const float rv = r[(size_t)tok * EEXP + e];
#pragma unroll
    for (int mi = 0; mi < 8; ++mi) {
      const int f = F0 + wr * 128 + mi * 16 + laneq * 4;   // 4 consecutive f
      const float4 b4 = *(const float4*)(b1 + e * FDIM + f);
      union { ushort4 u; __hip_bfloat16 h[4]; } pk;
      pk.h[0] = __float2bfloat16(gelu_fast(acc[mi][nj][0] + b4.x) * rv);
      pk.h[1] = __float2bfloat16(gelu_fast(acc[mi][nj][1] + b4.y) * rv);
      pk.h[2] = __float2bfloat16(gelu_fast(acc[mi][nj][2] + b4.z) * rv);
      pk.h[3] = __float2bfloat16(gelu_fast(acc[mi][nj][3] + b4.w) * rv);
      *(ushort4*)(Hs + (size_t)tok * EFK + e * FDIM + f) = pk.u;
    }
  }
}

// ---------------- GEMM 2: out[tok][d] = Hs[tok,:] @ W2flat[:,d] + sum_e r[tok,e]*b2[e,d]
// Grid: 256 blocks; decode puts the 4 d-quarter blocks of one token strip on
// the SAME XCD (bid%8 == strip%8) -> the strip's Hs rows L2-shared 4x.
__global__ __launch_bounds__(512, 2) void gemm_out_kernel(
    const __hip_bfloat16* __restrict__ Hs, const __hip_bfloat16* __restrict__ W2t,
    const float* __restrict__ b2, const float* __restrict__ r,
    float* __restrict__ out) {
  const int bid = blockIdx.x;
  const int strip = (bid >> 5) * 8 + (bid & 7);   // 0..63 token strip
  const int dq = (bid >> 3) & 3;                  // d quarter
  const int T0 = strip * 256, D0 = dq * 256;

  __shared__ char ldsb[2 * BUFSZ];   // 128 KiB

  const int tid = threadIdx.x, lane = tid & 63, wid = tid >> 6;
  const int wr = wid >> 2, wc = wid & 3;
  const int lanem = lane & 15, laneq = lane >> 4;
  const int l3 = lane >> 3, l7 = lane & 7;
  const int swz = lanem & 7;
  const int LDA_ = EFK, LDB_ = EFK;

  const __hip_bfloat16* gA = W2t + (size_t)D0 * EFK;
  const __hip_bfloat16* gB = Hs + (size_t)T0 * EFK;

  floatx4 acc[8][4];
#pragma unroll
  for (int i = 0; i < 8; ++i)
#pragma unroll
    for (int j = 0; j < 4; ++j) acc[i][j] = (floatx4){0.f, 0.f, 0.f, 0.f};
  short8 af[2][4][2], bf[4][2];

  GEMM_CORE(EFK / 64);

  // epilogue: combined bias sum_e r[tok,e]*b2[e,d], float4 store
#pragma unroll
  for (int mi = 0; mi < 8; ++mi) {
    const int d0 = D0 + wr * 128 + mi * 16 + laneq * 4;    // 4 consecutive d
    float4 b2v[EEXP];
#pragma unroll
    for (int e = 0; e < EEXP; ++e) b2v[e] = *(const float4*)(b2 + e * DDIM + d0);
#pragma unroll
    for (int nj = 0; nj < 4; ++nj) {
      const int tok = T0 + wc * 64 + nj * 16 + lanem;
      const float4* r4 = (const float4*)(r + (size_t)tok * EEXP);
      const float4 r0 = r4[0], r1 = r4[1];
      const float rv[EEXP] = {r0.x, r0.y, r0.z, r0.w, r1.x, r1.y, r1.z, r1.w};
      float bx = 0.f, by = 0.f, bz = 0.f, bw = 0.f;
#pragma unroll
      for (int e = 0; e < EEXP; ++e) {
        bx += rv[e] * b2v[e].x; by += rv[e] * b2v[e].y;
        bz += rv[e] * b2v[e].z; bw += rv[e] * b2v[e].w;
      }
      float4 o;
      o.x = acc[mi][nj][0] + bx; o.y = acc[mi][nj][1] + by;
      o.z = acc[mi][nj][2] + bz; o.w = acc[mi][nj][3] + bw;
      *(float4*)(out + (size_t)tok * DDIM + d0) = o;
    }
  }
}

extern "C" void kernel_launch(void* const* d_in, const int* in_sizes, int n_in,
                              void* d_out, int out_size, void* d_ws, size_t ws_size,
                              hipStream_t stream) {
  const float* x  = (const float*)d_in[0];
  const float* W1 = (const float*)d_in[1];
  const float* b1 = (const float*)d_in[2];
  const float* W2 = (const float*)d_in[3];
  const float* b2 = (const float*)d_in[4];
  const float* Wr = (const float*)d_in[5];
  const float* br = (const float*)d_in[6];
  float* out = (float*)d_out;

  char* ws = (char*)d_ws;
  __hip_bfloat16* xbf = (__hip_bfloat16*)(ws);                            // 32 MB
  __hip_bfloat16* W1t = (__hip_bfloat16*)(ws + (32u << 20));              // 8 MB  [E][F][D]
  __hip_bfloat16* W2t = (__hip_bfloat16*)(ws + (40u << 20));              // 8 MB  [D][E*F]
  float*          r   = (float*)(ws + (48u << 20));                       // 0.5 MB [MTOK][E]
  __hip_bfloat16* Hs  = (__hip_bfloat16*)(ws + (48u << 20) + (1u << 19)); // 128 MB [MTOK][E*F]

  // W1 [E][D][F] -> W1t [E][F][D]
  transpose_cast_kernel<<<dim3(FDIM / 32, DDIM / 32, EEXP), 256, 0, stream>>>(W1, W1t, DDIM, FDIM);
  // W2 [E*F][D] -> W2t [D][E*F]
  transpose_cast_kernel<<<dim3(DDIM / 32, EFK / 32, 1), 256, 0, stream>>>(W2, W2t, EFK, DDIM);
  // router softmax + x cast (one wave per token, 4096 blocks — R3-proven)
  router_cast_kernel<<<MTOK / 4, 256, 0, stream>>>(x, Wr, br, xbf, r);
  // stage 1 grouped GEMM (+gelu, +router scale): 256-f x 256-tok tiles
  gemm_h_kernel<<<dim3((MTOK / 256) * (FDIM / 256) * EEXP), 512, 0, stream>>>(xbf, W1t, b1, r, Hs);
  // stage 2 GEMM (+combined bias): 256-d x 256-tok tiles, XCD-grouped strips
  gemm_out_kernel<<<dim3((MTOK / 256) * (DDIM / 256)), 512, 0, stream>>>(Hs, W2t, b2, r, out);
}

// Round 10
// 479.381 us; speedup vs baseline: 1.3810x; 1.0005x over previous
//
#include <hip/hip_runtime.h>
#include <hip/hip_bf16.h>
#include <math.h>

// Problem constants
#define MTOK 16384   // B*N tokens
#define DDIM 1024
#define EEXP 8
#define FDIM 512
#define EFK  4096    // E*F flattened K for second GEMM

typedef __attribute__((ext_vector_type(8))) short short8;   // 8 bf16 = 4 VGPRs (MFMA A/B frag)
typedef __attribute__((ext_vector_type(4))) float floatx4;  // MFMA C/D frag

__device__ __forceinline__ void gld_lds16(const void* g, void* l) {
  // async global->LDS, 16B per lane, dest = wave-uniform base + lane*16
  __builtin_amdgcn_global_load_lds((const __attribute__((address_space(1))) void*)g,
                                   (__attribute__((address_space(3))) void*)l, 16, 0, 0);
}

// Fast exact-GELU via Abramowitz-Stegun 7.1.26 erf approx (|eps| <= 1.5e-7).
__device__ __forceinline__ float gelu_fast(float v) {
  const float z  = v * 0.70710678118654752f;
  const float az = fabsf(z);
  const float t  = __builtin_amdgcn_rcpf(1.f + 0.3275911f * az);
  const float poly = t * (0.254829592f +
                     t * (-0.284496736f +
                     t * (1.421413741f +
                     t * (-1.453152027f +
                     t * 1.061405429f))));
  const float ex = __expf(-az * az);
  float erfv = 1.f - poly * ex;
  erfv = copysignf(erfv, z);
  return 0.5f * v * (1.f + erfv);
}

// ---------------- merged transpose+cast for BOTH weight tensors (one launch).
// bid < 4096 : W1 expert slices [D][F] f32 -> W1t [F][D] bf16 (e = bid>>9)
// bid >= 4096: W2 [EFK][D] f32 -> W2t [D][EFK] bf16
__global__ __launch_bounds__(256) void transpose_cast_both(
    const float* __restrict__ W1, __hip_bfloat16* __restrict__ W1t,
    const float* __restrict__ W2, __hip_bfloat16* __restrict__ W2t) {
  __shared__ float tile[32][33];
  const int bid = blockIdx.x;
  const float* inb;
  __hip_bfloat16* outb;
  int R, C, c0, r0;
  if (bid < 4096) {
    const int e = bid >> 9, rem = bid & 511;
    R = DDIM; C = FDIM;                       // 32 r-blocks x 16 c-blocks
    inb  = W1 + (size_t)e * DDIM * FDIM;
    outb = W1t + (size_t)e * DDIM * FDIM;
    c0 = (rem & 15) * 32; r0 = (rem >> 4) * 32;
  } else {
    const int b2 = bid - 4096;
    R = EFK; C = DDIM;                        // 128 r-blocks x 32 c-blocks
    inb = W2; outb = W2t;
    c0 = (b2 & 31) * 32; r0 = (b2 >> 5) * 32;
  }
  const int tx = threadIdx.x & 31, ty = threadIdx.x >> 5;  // 32 x 8
#pragma unroll
  for (int i = 0; i < 4; ++i)
    tile[ty + i * 8][tx] = inb[(size_t)(r0 + ty + i * 8) * C + (c0 + tx)];
  __syncthreads();
#pragma unroll
  for (int i = 0; i < 4; ++i)
    outb[(size_t)(c0 + ty + i * 8) * R + (r0 + tx)] = __float2bfloat16(tile[tx][ty + i * 8]);
}

// ---------------- router softmax (fp32) + x -> bf16 cast. One wave per token
// (R3-proven structure, 4096 blocks; float2/ushort2 per-lane micro-vec).
__global__ __launch_bounds__(256) void router_cast_kernel(
    const float* __restrict__ x, const float* __restrict__ Wr, const float* __restrict__ br,
    __hip_bfloat16* __restrict__ xbf, float* __restrict__ r) {
  const int wave = (blockIdx.x * 256 + threadIdx.x) >> 6;  // token id
  const int lane = threadIdx.x & 63;
  const float* xr = x + (size_t)wave * DDIM;
  float acc[EEXP];
#pragma unroll
  for (int e = 0; e < EEXP; ++e) acc[e] = 0.f;
#pragma unroll
  for (int i = 0; i < DDIM / 128; ++i) {
    const int d = i * 128 + lane * 2;
    const float2 xv = *(const float2*)(xr + d);
    union { ushort2 u; __hip_bfloat16 h[2]; } pk;
    pk.h[0] = __float2bfloat16(xv.x);
    pk.h[1] = __float2bfloat16(xv.y);
    *(ushort2*)(xbf + (size_t)wave * DDIM + d) = pk.u;
    const float4* w4 = (const float4*)(Wr + (size_t)d * EEXP);
    const float4 w0 = w4[0], w1 = w4[1];   // row d
    const float4 w2 = w4[2], w3 = w4[3];   // row d+1
    acc[0] += xv.x * w0.x + xv.y * w2.x;
    acc[1] += xv.x * w0.y + xv.y * w2.y;
    acc[2] += xv.x * w0.z + xv.y * w2.z;
    acc[3] += xv.x * w0.w + xv.y * w2.w;
    acc[4] += xv.x * w1.x + xv.y * w3.x;
    acc[5] += xv.x * w1.y + xv.y * w3.y;
    acc[6] += xv.x * w1.z + xv.y * w3.z;
    acc[7] += xv.x * w1.w + xv.y * w3.w;
  }
#pragma unroll
  for (int off = 32; off; off >>= 1) {
#pragma unroll
    for (int e = 0; e < EEXP; ++e) acc[e] += __shfl_xor(acc[e], off, 64);
  }
  float mx = -1e30f;
#pragma unroll
  for (int e = 0; e < EEXP; ++e) { acc[e] += br[e]; mx = fmaxf(mx, acc[e]); }
  float s = 0.f;
#pragma unroll
  for (int e = 0; e < EEXP; ++e) { acc[e] = expf(acc[e] - mx); s += acc[e]; }
  const float inv = 1.f / s;
  if (lane < EEXP) r[(size_t)wave * EEXP + lane] = acc[lane] * inv;
}

// ============================================================================
// GEMM core = R3 structure (measured best of 7 variants: gemm_out 181.6 us,
// 32% MfmaUtil, 759 TF), with ONE single-variable change: the three mid-tile
// lgkm waits are now PURE HINTS (volatile asm, no "memory" clobber, no
// sched_barrier) — the m141 de-pinning experiment run cleanly inside the
// proven structure. Correctness is compiler-guaranteed: frag ds_reads are
// plain loads, so hipcc inserts precise per-dependency s_waitcnt before each
// MFMA regardless of our hints (m97 asm evidence). The structural
// vmcnt(0)+s_barrier fences keep their clobbers (they order buffer reuse).
// Also: dead final-iteration fence removed (conditional).
// 256x256 tile, BK=64, 8 waves (2Mx4N), XOR swizzle (PMC conflicts = 0),
// XCD grouping (FETCH 115 MB).
// ============================================================================
#define BUFSZ 65536
#define AOFF  0
#define BOFF  32768

#define STAGE_A(Q1, QM, K0)                                                        \
  do {                                                                             \
    _Pragma("unroll") for (int r_ = 0; r_ < 2; ++r_) {                             \
      gld_lds16(gA + (size_t)(r_ * 128 + (QM) * 64 + wid * 8 + l3) * LDA_ +        \
                    (K0) + ((l7 ^ l3) * 8),                                        \
                ldsb + (Q1) * BUFSZ + AOFF + (QM) * 16384 +                        \
                    (r_ * 64 + wid * 8) * 128);                                    \
    }                                                                              \
  } while (0)

#define STAGE_B(Q1, QN, K0)                                                        \
  do {                                                                             \
    _Pragma("unroll") for (int r_ = 0; r_ < 2; ++r_) {                             \
      const int lin_ = r_ * 64 + wid * 8 + l3;                                     \
      gld_lds16(gB + (size_t)((lin_ >> 5) * 64 + (QN) * 32 + (lin_ & 31)) * LDB_ + \
                    (K0) + ((l7 ^ l3) * 8),                                        \
                ldsb + (Q1) * BUFSZ + BOFF + (QN) * 16384 +                        \
                    (r_ * 64 + wid * 8) * 128);                                    \
    }                                                                              \
  } while (0)

#define STAGE_ALL(Q1, K0)                                                          \
  do { STAGE_A(Q1, 0, K0); STAGE_B(Q1, 0, K0); STAGE_B(Q1, 1, K0);                 \
       STAGE_A(Q1, 1, K0); } while (0)

#define READS_A(P, QM)                                                             \
  _Pragma("unroll") for (int i_ = 0; i_ < 4; ++i_)                                 \
    _Pragma("unroll") for (int k_ = 0; k_ < 2; ++k_)                               \
      af[QM][i_][k_] = *(const short8*)(ldsb + (P) * BUFSZ + AOFF +                \
          (QM) * 16384 + (wr * 64 + i_ * 16 + lanem) * 128 +                       \
          (((k_ * 4 + laneq) ^ swz) * 16));

#define READS_B(P)                                                                 \
  _Pragma("unroll") for (int n_ = 0; n_ < 4; ++n_)                                 \
    _Pragma("unroll") for (int k_ = 0; k_ < 2; ++k_)                               \
      bf[n_][k_] = *(const short8*)(ldsb + (P) * BUFSZ + BOFF +                    \
          (n_ >> 1) * 16384 + (wc * 32 + (n_ & 1) * 16 + lanem) * 128 +            \
          (((k_ * 4 + laneq) ^ swz) * 16));

#define MFMA_Q(QM, QN)                                                             \
  _Pragma("unroll") for (int k_ = 0; k_ < 2; ++k_)                                 \
    _Pragma("unroll") for (int i_ = 0; i_ < 4; ++i_)                               \
      _Pragma("unroll") for (int j_ = 0; j_ < 2; ++j_)                             \
        acc[(QM) * 4 + i_][(QN) * 2 + j_] =                                        \
            __builtin_amdgcn_mfma_f32_16x16x32_bf16(                               \
                af[QM][i_][k_], bf[(QN) * 2 + j_][k_],                             \
                acc[(QM) * 4 + i_][(QN) * 2 + j_], 0, 0, 0);

// Pure scheduling HINT: no clobber, no sched_barrier — compiler remains free
// to schedule loads/MFMAs around it; its own precise waits guarantee deps.
#define LGKM_HINT(N) asm volatile("s_waitcnt lgkmcnt(" #N ")")

#define GEMM_CORE(NT)                                                              \
  STAGE_ALL(0, 0);                                                                 \
  asm volatile("s_waitcnt vmcnt(0)\n\ts_barrier" ::: "memory");                    \
  for (int kt = 0; kt < (NT); ++kt) {                                              \
    const int p_ = kt & 1;                                                         \
    if (kt + 1 < (NT)) STAGE_ALL(p_ ^ 1, (kt + 1) * 64);                           \
    READS_A(p_, 0);                                                                \
    READS_B(p_);                                                                   \
    READS_A(p_, 1);                                                                \
    LGKM_HINT(12);                                                                 \
    __builtin_amdgcn_s_setprio(1);                                                 \
    MFMA_Q(0, 0);                                                                  \
    __builtin_amdgcn_s_setprio(0);                                                 \
    LGKM_HINT(8);                                                                  \
    __builtin_amdgcn_s_setprio(1);                                                 \
    MFMA_Q(0, 1);                                                                  \
    __builtin_amdgcn_s_setprio(0);                                                 \
    LGKM_HINT(0);                                                                  \
    __builtin_amdgcn_s_setprio(1);                                                 \
    MFMA_Q(1, 1);                                                                  \
    MFMA_Q(1, 0);                                                                  \
    __builtin_amdgcn_s_setprio(0);                                                 \
    if (kt + 1 < (NT))                                                             \
      asm volatile("s_waitcnt vmcnt(0)\n\ts_barrier" ::: "memory");                \
  }

// ---------------- GEMM 1: Hs[tok][e*F+f] = bf16( gelu(x @ W1[e] + b1[e]) * r[tok,e] )
// Grid: 1024 blocks = e(8) x fb(2) x strip(64); strip fastest so the 16 blocks
// sharing a token strip are 64 apart in bid -> same XCD (64%8==0) -> x strip
// L2-resident; each (e,fb) weight slice dispatch-adjacent.
__global__ __launch_bounds__(512, 2) void gemm_h_kernel(
    const __hip_bfloat16* __restrict__ A, const __hip_bfloat16* __restrict__ W1t,
    const float* __restrict__ b1, const float* __restrict__ r,
    __hip_bfloat16* __restrict__ Hs) {
  const int bid = blockIdx.x;
  const int strip = bid & 63, fb = (bid >> 6) & 1, e = bid >> 7;
  const int T0 = strip * 256, F0 = fb * 256;

  __shared__ char ldsb[2 * BUFSZ];   // 128 KiB

  const int tid = threadIdx.x, lane = tid & 63, wid = tid >> 6;
  const int wr = wid >> 2, wc = wid & 3;       // 2 x 4 wave grid
  const int lanem = lane & 15, laneq = lane >> 4;
  const int l3 = lane >> 3, l7 = lane & 7;     // staging lane decompose
  const int swz = lanem & 7;
  const int LDA_ = DDIM, LDB_ = DDIM;

  const __hip_bfloat16* gA = W1t + (size_t)e * FDIM * DDIM + (size_t)F0 * DDIM;
  const __hip_bfloat16* gB = A + (size_t)T0 * DDIM;

  floatx4 acc[8][4];
#pragma unroll
  for (int i = 0; i < 8; ++i)
#pragma unroll
    for (int j = 0; j < 4; ++j) acc[i][j] = (floatx4){0.f, 0.f, 0.f, 0.f};
  short8 af[2][4][2], bf[4][2];

  GEMM_CORE(DDIM / 64);

  // epilogue: bias -> fast exact-gelu -> router scale -> packed bf16x4 store
#pragma unroll
  for (int nj = 0; nj < 4; ++nj) {
    const int tok = T0 + wc * 64 + nj * 16 + lanem;
    const float rv = r[(size_t)tok * EEXP + e];
#pragma unroll
    for (int mi = 0; mi < 8; ++mi) {
      const int f = F0 + wr * 128 + mi * 16 + laneq * 4;   // 4 consecutive f
      const float4 b4 = *(const float4*)(b1 + e * FDIM + f);
      union { ushort4 u; __hip_bfloat16 h[4]; } pk;
      pk.h[0] = __float2bfloat16(gelu_fast(acc[mi][nj][0] + b4.x) * rv);
      pk.h[1] = __float2bfloat16(gelu_fast(acc[mi][nj][1] + b4.y) * rv);
      pk.h[2] = __float2bfloat16(gelu_fast(acc[mi][nj][2] + b4.z) * rv);
      pk.h[3] = __float2bfloat16(gelu_fast(acc[mi][nj][3] + b4.w) * rv);
      *(ushort4*)(Hs + (size_t)tok * EFK + e * FDIM + f) = pk.u;
    }
  }
}

// ---------------- GEMM 2: out[tok][d] = Hs[tok,:] @ W2flat[:,d] + sum_e r[tok,e]*b2[e,d]
// Grid: 256 blocks; decode puts the 4 d-quarter blocks of one token strip on
// the SAME XCD (bid%8 == strip%8) -> the strip's Hs rows L2-shared 4x.
__global__ __launch_bounds__(512, 2) void gemm_out_kernel(
    const __hip_bfloat16* __restrict__ Hs, const __hip_bfloat16* __restrict__ W2t,
    const float* __restrict__ b2, const float* __restrict__ r,
    float* __restrict__ out) {
  const int bid = blockIdx.x;
  const int strip = (bid >> 5) * 8 + (bid & 7);   // 0..63 token strip
  const int dq = (bid >> 3) & 3;                  // d quarter
  const int T0 = strip * 256, D0 = dq * 256;

  __shared__ char ldsb[2 * BUFSZ];   // 128 KiB

  const int tid = threadIdx.x, lane = tid & 63, wid = tid >> 6;
  const int wr = wid >> 2, wc = wid & 3;
  const int lanem = lane & 15, laneq = lane >> 4;
  const int l3 = lane >> 3, l7 = lane & 7;
  const int swz = lanem & 7;
  const int LDA_ = EFK, LDB_ = EFK;

  const __hip_bfloat16* gA = W2t + (size_t)D0 * EFK;
  const __hip_bfloat16* gB = Hs + (size_t)T0 * EFK;

  floatx4 acc[8][4];
#pragma unroll
  for (int i = 0; i < 8; ++i)
#pragma unroll
    for (int j = 0; j < 4; ++j) acc[i][j] = (floatx4){0.f, 0.f, 0.f, 0.f};
  short8 af[2][4][2], bf[4][2];

  GEMM_CORE(EFK / 64);

  // epilogue: combined bias sum_e r[tok,e]*b2[e,d], float4 store
#pragma unroll
  for (int mi = 0; mi < 8; ++mi) {
    const int d0 = D0 + wr * 128 + mi * 16 + laneq * 4;    // 4 consecutive d
    float4 b2v[EEXP];
#pragma unroll
    for (int e = 0; e < EEXP; ++e) b2v[e] = *(const float4*)(b2 + e * DDIM + d0);
#pragma unroll
    for (int nj = 0; nj < 4; ++nj) {
      const int tok = T0 + wc * 64 + nj * 16 + lanem;
      const float4* r4 = (const float4*)(r + (size_t)tok * EEXP);
      const float4 r0 = r4[0], r1 = r4[1];
      const float rv[EEXP] = {r0.x, r0.y, r0.z, r0.w, r1.x, r1.y, r1.z, r1.w};
      float bx = 0.f, by = 0.f, bz = 0.f, bw = 0.f;
#pragma unroll
      for (int e = 0; e < EEXP; ++e) {
        bx += rv[e] * b2v[e].x; by += rv[e] * b2v[e].y;
        bz += rv[e] * b2v[e].z; bw += rv[e] * b2v[e].w;
      }
      float4 o;
      o.x = acc[mi][nj][0] + bx; o.y = acc[mi][nj][1] + by;
      o.z = acc[mi][nj][2] + bz; o.w = acc[mi][nj][3] + bw;
      *(float4*)(out + (size_t)tok * DDIM + d0) = o;
    }
  }
}

extern "C" void kernel_launch(void* const* d_in, const int* in_sizes, int n_in,
                              void* d_out, int out_size, void* d_ws, size_t ws_size,
                              hipStream_t stream) {
  const float* x  = (const float*)d_in[0];
  const float* W1 = (const float*)d_in[1];
  const float* b1 = (const float*)d_in[2];
  const float* W2 = (const float*)d_in[3];
  const float* b2 = (const float*)d_in[4];
  const float* Wr = (const float*)d_in[5];
  const float* br = (const float*)d_in[6];
  float* out = (float*)d_out;

  char* ws = (char*)d_ws;
  __hip_bfloat16* xbf = (__hip_bfloat16*)(ws);                            // 32 MB
  __hip_bfloat16* W1t = (__hip_bfloat16*)(ws + (32u << 20));              // 8 MB  [E][F][D]
  __hip_bfloat16* W2t = (__hip_bfloat16*)(ws + (40u << 20));              // 8 MB  [D][E*F]
  float*          r   = (float*)(ws + (48u << 20));                       // 0.5 MB [MTOK][E]
  __hip_bfloat16* Hs  = (__hip_bfloat16*)(ws + (48u << 20) + (1u << 19)); // 128 MB [MTOK][E*F]

  // both weight transposes in one launch (W1 -> W1t, W2 -> W2t)
  transpose_cast_both<<<8192, 256, 0, stream>>>(W1, W1t, W2, W2t);
  // router softmax + x cast (one wave per token, 4096 blocks)
  router_cast_kernel<<<MTOK / 4, 256, 0, stream>>>(x, Wr, br, xbf, r);
  // stage 1 grouped GEMM (+gelu, +router scale): 256-f x 256-tok tiles
  gemm_h_kernel<<<dim3((MTOK / 256) * (FDIM / 256) * EEXP), 512, 0, stream>>>(xbf, W1t, b1, r, Hs);
  // stage 2 GEMM (+combined bias): 256-d x 256-tok tiles, XCD-grouped strips
  gemm_out_kernel<<<dim3((MTOK / 256) * (DDIM / 256)), 512, 0, stream>>>(Hs, W2t, b2, r, out);
}